// Round 8
// baseline (146.636 us; speedup 1.0000x reference)
//
#include <hip/hip_runtime.h>

// Problem constants (fixed by setup_inputs): B=4096, D=512, H=W=64, N=4096.
#define B_ROWS 4096
#define N_COLS 4096
#define DIM    512
#define LDK    1024   // row stride (elements) of split bf16 arrays [hi(512) | lo(512)]
#define STAGE  16384  // shorts per ring stage (32 KB): Ah|Al|Bh|Bl, each 128x32

typedef __attribute__((ext_vector_type(8))) short short8;
typedef __attribute__((ext_vector_type(4))) float floatx4;

// bf16 round-to-nearest-even split helpers (bit-exact, no API dependence)
__device__ __forceinline__ unsigned short f2bf_rn(float f) {
    unsigned u = __float_as_uint(f);
    u += 0x7fffu + ((u >> 16) & 1u);
    return (unsigned short)(u >> 16);
}
__device__ __forceinline__ float bf2f(unsigned short h) {
    return __uint_as_float(((unsigned)h) << 16);
}

// Monotone float->uint map; (key<<32)|idx gives u64 atomicMin argmin with
// smallest-index tie-break (matches numpy argmin semantics).
__device__ __forceinline__ unsigned long long pack_key(float v, int idx) {
    unsigned u = __float_as_uint(v);
    u = (u & 0x80000000u) ? ~u : (u | 0x80000000u);
    return ((unsigned long long)u << 32) | (unsigned)idx;
}

// Async global->LDS, 16B per lane. LDS dest is wave-uniform base + lane*16.
__device__ __forceinline__ void async16(const unsigned short* g, unsigned short* l) {
    __builtin_amdgcn_global_load_lds(
        (__attribute__((address_space(1))) void*)g,
        (__attribute__((address_space(3))) void*)l, 16, 0, 0);
}

// One wave per row (4 rows/block): split fp32 row into bf16 hi/lo halves,
// compute exact fp32 ||row||^2, init packed argmin accumulators.
__global__ __launch_bounds__(256) void som_convert(
    const float* __restrict__ X, const float* __restrict__ Wt,
    unsigned short* __restrict__ Xc, unsigned short* __restrict__ Wc,
    float* __restrict__ x_sq, float* __restrict__ w_sq,
    unsigned long long* __restrict__ packed)
{
    int wave = threadIdx.x >> 6, lane = threadIdx.x & 63;
    int grow = blockIdx.x * 4 + wave;            // 0..8191
    bool isX = grow < B_ROWS;
    const float* src = isX ? (X + (size_t)grow * DIM)
                           : (Wt + (size_t)(grow - B_ROWS) * DIM);
    const float4* p4 = (const float4*)src;
    float4 a = p4[lane * 2], b = p4[lane * 2 + 1];
    float f[8] = {a.x, a.y, a.z, a.w, b.x, b.y, b.z, b.w};
    unsigned short hi[8], lo[8];
    float s = 0.f;
    #pragma unroll
    for (int t = 0; t < 8; ++t) {
        hi[t] = f2bf_rn(f[t]);
        lo[t] = f2bf_rn(f[t] - bf2f(hi[t]));
        s = fmaf(f[t], f[t], s);
    }
    unsigned short* dst = (isX ? Xc + (size_t)grow * LDK
                               : Wc + (size_t)(grow - B_ROWS) * LDK) + lane * 8;
    *(ushort4*)(dst)       = make_ushort4(hi[0], hi[1], hi[2], hi[3]);
    *(ushort4*)(dst + 4)   = make_ushort4(hi[4], hi[5], hi[6], hi[7]);
    *(ushort4*)(dst + 512) = make_ushort4(lo[0], lo[1], lo[2], lo[3]);
    *(ushort4*)(dst + 516) = make_ushort4(lo[4], lo[5], lo[6], lo[7]);
    #pragma unroll
    for (int off = 32; off >= 1; off >>= 1) s += __shfl_xor(s, off, 64);
    if (lane == 0) {
        if (isX) { x_sq[grow] = s; packed[grow] = ~0ull; }
        else     { w_sq[grow - B_ROWS] = s; }
    }
}

// Split-bf16 distance GEMM + fused per-row argmin.
// PRODUCER-CONSUMER RING (the R7->R8 change): R7 proved the kernel is
// stall-bound (conflicts 0, time unchanged, MfmaUtil pinned at 35% = the
// m97 2-barrier plateau: every K-iter drains vmcnt(0) at the barrier).
// Restructure: wave 4 = producer (stages ring of 2 x 32KB BK=32 slices via
// global_load_lds, waits only on ITS OWN vmcnt), waves 0..3 = consumers
// (poll an LDS flag, ds_read fragments, 48 MFMAs; NEVER execute a vmcnt
// drain). No __syncthreads in the K-loop. LDS chunk swizzle kept (R7:
// conflicts -> 0). Sync via volatile LDS + ds atomics:
//   prod_flag[s] = last generation staged into stage s, +1
//   cons_cnt[s]  = total consumer-wave completions on stage s
// Consumer bumps cons_cnt AFTER its MFMAs (register data-deps force all
// fragment ds_reads to precede; __threadfence_block makes it airtight).
__global__ __launch_bounds__(320, 2) void som_dist_bf16(
    const unsigned short* __restrict__ Xc, const unsigned short* __restrict__ Wc,
    const float* __restrict__ w_sq, unsigned long long* __restrict__ packed)
{
    __shared__ unsigned short buf[2 * STAGE];   // 64 KB ring
    __shared__ unsigned syncw[4];               // [0..1] prod_flag, [2..3] cons_cnt
    volatile unsigned* vs = syncw;
    const int tid  = threadIdx.x;
    const int wave = tid >> 6, lane = tid & 63;
    const int bm = blockIdx.y, bn = blockIdx.x;

    if (tid < 4) syncw[tid] = 0;
    __syncthreads();                            // ONLY barrier in this kernel

    // Staging lane map (swizzled chunks; same as R7):
    const int srow = lane >> 2;                        // 0..15 row in group
    const int schunk = (lane & 3) ^ ((lane >> 3) & 3); // swizzled 16B chunk
    const int scol = schunk * 8;

    if (wave == 4) {
        // ---------------- producer ----------------
        const unsigned short* gA = Xc + (size_t)(bm * 128 + srow) * LDK + scol;
        const unsigned short* gB = Wc + (size_t)(bn * 128 + srow) * LDK + scol;
        #pragma unroll 1
        for (int g = 0; g < 16; ++g) {
            const int s = g & 1;
            const int k0 = g * 32;
            if (g >= 2) {
                const unsigned need = 4u * (unsigned)((g - s) >> 1);
                while (vs[2 + s] < need) __builtin_amdgcn_s_sleep(1);
            }
            unsigned short* st = &buf[s * STAGE];
            #pragma unroll
            for (int rg = 0; rg < 8; ++rg)   // Ah
                async16(gA + (size_t)(rg * 16) * LDK + k0, st + rg * 16 * 32);
            #pragma unroll
            for (int rg = 0; rg < 8; ++rg)   // Al
                async16(gA + (size_t)(rg * 16) * LDK + k0 + 512, st + 4096 + rg * 16 * 32);
            #pragma unroll
            for (int rg = 0; rg < 8; ++rg)   // Bh
                async16(gB + (size_t)(rg * 16) * LDK + k0, st + 8192 + rg * 16 * 32);
            #pragma unroll
            for (int rg = 0; rg < 8; ++rg)   // Bl
                async16(gB + (size_t)(rg * 16) * LDK + k0 + 512, st + 12288 + rg * 16 * 32);
            // Wait for OUR loads only; consumers never execute this.
            asm volatile("s_waitcnt vmcnt(0)" ::: "memory");
            if (lane == 0) vs[s] = (unsigned)(g + 1);
        }
        return;
    }

    // ---------------- consumers (waves 0..3) ----------------
    const int wr = wave >> 1, wc = wave & 1;       // 2x2 wave grid
    const int quad = lane >> 4, t16 = lane & 15;
    const int fslot = (quad ^ ((t16 >> 1) & 3)) * 8;   // un-swizzle
    const int arow = (wr * 64 + t16) * 32 + fslot;
    const int brow = (wc * 64 + t16) * 32 + fslot;

    floatx4 acc[4][4];
    #pragma unroll
    for (int i = 0; i < 4; ++i)
        #pragma unroll
        for (int j = 0; j < 4; ++j) acc[i][j] = (floatx4){0.f, 0.f, 0.f, 0.f};

    #pragma unroll 1
    for (int g = 0; g < 16; ++g) {
        const int s = g & 1;
        while (vs[s] < (unsigned)(g + 1)) __builtin_amdgcn_s_sleep(1);
        const unsigned short* st = &buf[s * STAGE];

        short8 ah[4], al[4], bh[4], bl[4];
        #pragma unroll
        for (int i = 0; i < 4; ++i) ah[i] = *(const short8*)(st + arow + i * 16 * 32);
        #pragma unroll
        for (int i = 0; i < 4; ++i) al[i] = *(const short8*)(st + 4096 + arow + i * 16 * 32);
        #pragma unroll
        for (int j = 0; j < 4; ++j) bh[j] = *(const short8*)(st + 8192 + brow + j * 16 * 32);
        #pragma unroll
        for (int j = 0; j < 4; ++j) bl[j] = *(const short8*)(st + 12288 + brow + j * 16 * 32);

        #pragma unroll
        for (int i = 0; i < 4; ++i)
            #pragma unroll
            for (int j = 0; j < 4; ++j)
                acc[i][j] = __builtin_amdgcn_mfma_f32_16x16x32_bf16(
                    ah[i], bh[j], acc[i][j], 0, 0, 0);
        #pragma unroll
        for (int i = 0; i < 4; ++i)
            #pragma unroll
            for (int j = 0; j < 4; ++j)
                acc[i][j] = __builtin_amdgcn_mfma_f32_16x16x32_bf16(
                    ah[i], bl[j], acc[i][j], 0, 0, 0);
        #pragma unroll
        for (int i = 0; i < 4; ++i)
            #pragma unroll
            for (int j = 0; j < 4; ++j)
                acc[i][j] = __builtin_amdgcn_mfma_f32_16x16x32_bf16(
                    al[i], bh[j], acc[i][j], 0, 0, 0);

        // Mark stage consumed (after MFMAs: register deps guarantee all
        // fragment ds_reads above have executed; fence makes it airtight).
        __threadfence_block();
        if (lane == 0) atomicAdd(&syncw[2 + s], 1u);
    }

    // Epilogue: val = w_sq - 2*dot (x_sq per-row const, irrelevant to argmin).
    // C/D layout: col = t16, row = quad*4 + reg  [m89/m91].
    const int col0 = bn * 128 + wc * 64 + t16;
    float wq[4];
    #pragma unroll
    for (int j = 0; j < 4; ++j) wq[j] = w_sq[col0 + j * 16];
    const int row_base = bm * 128 + wr * 64 + quad * 4;
    #pragma unroll
    for (int i = 0; i < 4; ++i) {
        #pragma unroll
        for (int r = 0; r < 4; ++r) {
            unsigned long long best = ~0ull;
            #pragma unroll
            for (int j = 0; j < 4; ++j) {
                float val = fmaf(-2.f, acc[i][j][r], wq[j]);
                unsigned long long key = pack_key(val, col0 + j * 16);
                best = (key < best) ? key : best;
            }
            #pragma unroll
            for (int m = 1; m <= 8; m <<= 1) {     // reduce 16-lane col group
                unsigned long long o = __shfl_xor(best, m, 64);
                best = (o < best) ? o : best;
            }
            if (t16 == 0)
                atomicMin(&packed[row_base + i * 16 + r], best);
        }
    }
}

// Unpack argmin, qe = sqrt(max(||x||^2 + val, 0)).
// d_out: bmu_indices (4096 x 2) flat, then qe (4096), all float.
__global__ __launch_bounds__(256) void som_finalize(
    const unsigned long long* __restrict__ packed,
    const float* __restrict__ x_sq, float* __restrict__ out)
{
    int b = blockIdx.x * 256 + threadIdx.x;  // 0..4095
    unsigned long long p = packed[b];
    unsigned idx = (unsigned)(p & 0xffffffffull);
    unsigned key = (unsigned)(p >> 32);
    unsigned u = (key & 0x80000000u) ? (key & 0x7fffffffu) : ~key;
    float val = __uint_as_float(u);
    float sq = fmaxf(x_sq[b] + val, 0.f);
    out[2 * b]     = (float)(idx >> 6);   // y = idx / 64
    out[2 * b + 1] = (float)(idx & 63);   // x = idx % 64
    out[2 * B_ROWS + b] = sqrtf(sq);
}

extern "C" void kernel_launch(void* const* d_in, const int* in_sizes, int n_in,
                              void* d_out, int out_size, void* d_ws, size_t ws_size,
                              hipStream_t stream) {
    const float* X  = (const float*)d_in[0];   // (4096, 512)
    const float* Wt = (const float*)d_in[1];   // (64, 64, 512) -> (4096, 512)
    float* out = (float*)d_out;

    // ws layout: [0,32K) packed u64[4096]; [32K,48K) x_sq; [48K,64K) w_sq;
    // [64K, 64K+8M) Xc bf16 split; [64K+8M, 64K+16M) Wc bf16 split.
    unsigned long long* packed = (unsigned long long*)d_ws;
    float* x_sq = (float*)((char*)d_ws + (32 << 10));
    float* w_sq = (float*)((char*)d_ws + (48 << 10));
    unsigned short* Xc = (unsigned short*)((char*)d_ws + (64 << 10));
    unsigned short* Wc = (unsigned short*)((char*)d_ws + (64 << 10) + ((size_t)B_ROWS * LDK * 2));

    som_convert<<<dim3((B_ROWS + N_COLS) / 4), dim3(256), 0, stream>>>(
        X, Wt, Xc, Wc, x_sq, w_sq, packed);
    som_dist_bf16<<<dim3(N_COLS / 128, B_ROWS / 128), dim3(320), 0, stream>>>(
        Xc, Wc, w_sq, packed);
    som_finalize<<<dim3(B_ROWS / 256), dim3(256), 0, stream>>>(packed, x_sq, out);
}